// Round 16
// baseline (376.096 us; speedup 1.0000x reference)
//
#include <hip/hip_runtime.h>

#define NNODES 100000
#define NEDGES 3200000
#define NPG 200
#define NGRAPH 500
#define FIN 128
#define HID 32
#define KP 50
#define NCLS 10

#define NB1 196      // ceil(100000/512) dst-buckets
#define BSH 9
#define CHUNK 8192
#define NBLK1 391    // ceil(NEDGES/CHUNK)
#define CAP 17408    // per-bucket slot capacity (mean 16384 + 8 sigma)

// ---------------- level-1 place: LDS-binned partition, direct bucket reservation ----------------
__global__ __launch_bounds__(512) void k_place1(const int* __restrict__ src,
                                                const int* __restrict__ dst,
                                                int* __restrict__ cursor,
                                                unsigned* __restrict__ csorted) {
    __shared__ int hist[NB1];
    __shared__ int lstart[NB1];
    __shared__ int base[NB1];
    __shared__ int cnt2[NB1];
    __shared__ int sarr[256];
    __shared__ unsigned buf[CHUNK];
    __shared__ int dbuf[CHUNK];
    int t = threadIdx.x;
    for (int i = t; i < NB1; i += 512) { hist[i] = 0; cnt2[i] = 0; }
    __syncthreads();
    int eb = blockIdx.x * CHUNK;
    for (int i = 0; i < CHUNK / 512; ++i) {
        int e = eb + t + i * 512;
        if (e < NEDGES) {
            int s = src[e], d = dst[e];
            if (s != d) atomicAdd(&hist[d >> BSH], 1);
        }
    }
    __syncthreads();
    if (t < 256) sarr[t] = (t < NB1) ? hist[t] : 0;
    __syncthreads();
    for (int ofs = 1; ofs < 256; ofs <<= 1) {
        int add = (t < 256 && t >= ofs) ? sarr[t - ofs] : 0;
        __syncthreads();
        if (t < 256) sarr[t] += add;
        __syncthreads();
    }
    if (t < NB1) {
        lstart[t] = (t == 0) ? 0 : sarr[t - 1];
        base[t] = hist[t] ? (t * CAP + atomicAdd(&cursor[t], hist[t])) : 0;
    }
    __syncthreads();
    for (int i = 0; i < CHUNK / 512; ++i) {
        int e = eb + t + i * 512;
        if (e < NEDGES) {
            int s = src[e], d = dst[e];
            if (s != d) {
                int bk = d >> BSH;
                int pos = atomicAdd(&cnt2[bk], 1);
                int slot = lstart[bk] + pos;
                buf[slot] = ((unsigned)s << BSH) | (unsigned)(d & 511);
                dbuf[slot] = base[bk] + pos;
            }
        }
    }
    __syncthreads();
    int nval = sarr[NB1 - 1];
    for (int j = t; j < nval; j += 512) csorted[dbuf[j]] = buf[j];
}

// ---------------- level-2: per-bucket CSR finalize (+begend, +dinv) ----------------
__global__ __launch_bounds__(512) void k_fill2(const int* __restrict__ cursor,
                                               const unsigned* __restrict__ csorted,
                                               int* __restrict__ csrc,
                                               int2* __restrict__ begend,
                                               float* __restrict__ dinv) {
    __shared__ int cnt[512];
    __shared__ int loffs[512];
    __shared__ int cnt2[512];
    __shared__ int sarr[512];
    int b = blockIdx.x, t = threadIdx.x;
    cnt[t] = 0; cnt2[t] = 0;
    __syncthreads();
    int base = b * CAP;
    int m = cursor[b];
    for (int j = t; j < m; j += 512) atomicAdd(&cnt[csorted[base + j] & 511], 1);
    __syncthreads();
    sarr[t] = cnt[t];
    __syncthreads();
    for (int ofs = 1; ofs < 512; ofs <<= 1) {
        int add = (t >= ofs) ? sarr[t - ofs] : 0;
        __syncthreads();
        sarr[t] += add;
        __syncthreads();
    }
    loffs[t] = sarr[t] - cnt[t];  // exclusive
    __syncthreads();
    int n = b * 512 + t;
    if (n < NNODES) {
        int beg = base + loffs[t];
        begend[n] = make_int2(beg, beg + cnt[t]);
        dinv[n] = rsqrtf((float)cnt[t] + 1.0f);
    }
    for (int j = t; j < m; j += 512) {
        unsigned p = csorted[base + j];
        int d = p & 511;
        int pos = atomicAdd(&cnt2[d], 1);
        csrc[base + loffs[d] + pos] = (int)(p >> BSH);
    }
}

// ---------------- hw = (X @ W) * dinv : 256 rows/block, thread = 8 rows x 4 cols ----------------
__global__ __launch_bounds__(256) void k_matmul(const float* __restrict__ X, int ldx, int K,
                                                const float* __restrict__ W,
                                                const float* __restrict__ dinv,
                                                float* __restrict__ h) {
    __shared__ float Xk[32 * 256];  // k-major slab, 32 KB
    __shared__ float Wl[32 * 36];   // padded, 4.6 KB
    int t = threadIdx.x;
    int tx = t & 7;    // col quad: cols 4tx..4tx+3
    int ty = t >> 3;   // 0..31: row quads ty and 32+ty
    int n0 = blockIdx.x * 256;
    float acc[8][4];
#pragma unroll
    for (int r = 0; r < 8; ++r)
#pragma unroll
        for (int c = 0; c < 4; ++c) acc[r][c] = 0.f;

    int ksteps = K >> 5;
    for (int ks = 0; ks < ksteps; ++ks) {
        int kbase = ks << 5;
        __syncthreads();
        for (int idx = t; idx < 256 * 8; idx += 256) {
            int row = idx >> 3, c4 = (idx & 7) * 4;
            float4 v = make_float4(0.f, 0.f, 0.f, 0.f);
            if (n0 + row < NNODES)
                v = *reinterpret_cast<const float4*>(X + (size_t)(n0 + row) * ldx + kbase + c4);
            float vv[4] = {v.x, v.y, v.z, v.w};
#pragma unroll
            for (int j = 0; j < 4; ++j) {
                int k = c4 + j;
                int gp = (row >> 2) ^ ((k >> 2) & 31);
                Xk[k * 256 + gp * 4 + (row & 3)] = vv[j];
            }
        }
        for (int idx = t; idx < 32 * 32; idx += 256) {
            int k = idx >> 5, j = idx & 31;
            Wl[k * 36 + j] = W[(size_t)(kbase + k) * HID + j];
        }
        __syncthreads();
        const float4* Xq = reinterpret_cast<const float4*>(Xk);
        const float4* Wq = reinterpret_cast<const float4*>(Wl);
        for (int k = 0; k < 32; ++k) {
            int key = (k >> 2) & 31;
            float4 a0 = Xq[k * 64 + (ty ^ key)];
            float4 a1 = Xq[k * 64 + 32 + (ty ^ key)];
            float4 wv = Wq[k * 9 + tx];
            float a[8] = {a0.x, a0.y, a0.z, a0.w, a1.x, a1.y, a1.z, a1.w};
#pragma unroll
            for (int r = 0; r < 8; ++r) {
                acc[r][0] += a[r] * wv.x;
                acc[r][1] += a[r] * wv.y;
                acc[r][2] += a[r] * wv.z;
                acc[r][3] += a[r] * wv.w;
            }
        }
    }
#pragma unroll
    for (int r = 0; r < 8; ++r) {
        int row = (r < 4) ? (4 * ty + r) : (128 + 4 * ty + (r - 4));
        int gr = n0 + row;
        if (gr < NNODES) {
            float di = dinv[gr];
            float4 v = make_float4(acc[r][0] * di, acc[r][1] * di, acc[r][2] * di, acc[r][3] * di);
            *reinterpret_cast<float4*>(h + (size_t)gr * HID + 4 * tx) = v;
        }
    }
}

// ---------------- gather: 2 nodes/wave, 8-deep unroll, unmasked fast path ----------------
__global__ __launch_bounds__(256) void k_gather(const int2* __restrict__ begend,
                                                const int* __restrict__ csrc,
                                                const float* __restrict__ dinv,
                                                const float* __restrict__ hw,
                                                const float* __restrict__ bias,
                                                float* __restrict__ xc, int coloff) {
    int t = threadIdx.x;
    int wv = t >> 6;
    int lane = t & 63;
    int nh = lane >> 5;    // node half within wave
    int sub = lane & 31;
    int g = sub >> 3;      // edge slot 0..3
    int q = sub & 7;       // channel quad 0..7
    int n = blockIdx.x * 8 + wv * 2 + nh;
    int2 be = begend[n];
    int beg = be.x, end = be.y, last = end - 1;
    float4 acc = make_float4(0.f, 0.f, 0.f, 0.f);
    int e0 = beg + g;
    for (; e0 + 28 < end; e0 += 32) {
#pragma unroll
        for (int j = 0; j < 8; ++j) {
            int s = csrc[e0 + 4 * j];
            float4 hv = *reinterpret_cast<const float4*>(hw + (size_t)s * HID + q * 4);
            acc.x += hv.x; acc.y += hv.y; acc.z += hv.z; acc.w += hv.w;
        }
    }
    if (e0 < end) {
#pragma unroll
        for (int j = 0; j < 8; ++j) {
            int e = e0 + 4 * j;
            float mk = (e <= last) ? 1.f : 0.f;
            int s = csrc[min(e, last)];
            float4 hv = *reinterpret_cast<const float4*>(hw + (size_t)s * HID + q * 4);
            acc.x += mk * hv.x; acc.y += mk * hv.y; acc.z += mk * hv.z; acc.w += mk * hv.w;
        }
    }
    for (int m = 8; m <= 16; m <<= 1) {
        acc.x += __shfl_xor(acc.x, m, 64);
        acc.y += __shfl_xor(acc.y, m, 64);
        acc.z += __shfl_xor(acc.z, m, 64);
        acc.w += __shfl_xor(acc.w, m, 64);
    }
    if (g == 0) {
        float di = dinv[n];
        float4 hv = *reinterpret_cast<const float4*>(hw + (size_t)n * HID + q * 4);
        float4 bv = *reinterpret_cast<const float4*>(bias + q * 4);
        float4 v;
        v.x = tanhf(di * (acc.x + hv.x) + bv.x);
        v.y = tanhf(di * (acc.y + hv.y) + bv.y);
        v.z = tanhf(di * (acc.z + hv.z) + bv.z);
        v.w = tanhf(di * (acc.w + hv.w) + bv.w);
        *reinterpret_cast<float4*>(xc + (size_t)n * 96 + coloff + q * 4) = v;
    }
}

// ---------------- stable top-50 sort-pool per graph ----------------
__global__ __launch_bounds__(256) void k_sortpool(const float* __restrict__ xc,
                                                  float* __restrict__ pooled) {
    int g = blockIdx.x;
    __shared__ float vals[NPG];
    __shared__ int sel[KP];
    int t = threadIdx.x;
    if (t < NPG) vals[t] = xc[((size_t)g * NPG + t) * 96 + 95];
    __syncthreads();
    if (t < NPG) {
        float v = vals[t];
        int r = 0;
        for (int k = 0; k < NPG; ++k) {
            float vk = vals[k];
            r += (vk > v) || (vk == v && k < t);
        }
        if (r < KP) sel[r] = t;
    }
    __syncthreads();
    for (int idx = t; idx < KP * 24; idx += 256) {
        int r = idx / 24, c4 = (idx % 24) * 4;
        *reinterpret_cast<float4*>(pooled + (size_t)g * KP * 96 + r * 96 + c4) =
            *reinterpret_cast<const float4*>(xc + ((size_t)g * NPG + sel[r]) * 96 + c4);
    }
}

// ---------------- capsule-1 priors: 256x128 tile, 512 thr, 8x8/thread ----------------
// K=96 in two 48-halves; half-1 global loads issued into registers DURING half-0 compute
__global__ __launch_bounds__(512, 2) void k_priors1(const float* __restrict__ pooled,
                                                    const float* __restrict__ Wc1,
                                                    float* __restrict__ priors) {
    int bid = blockIdx.x;
    int ct = bid & 3;          // 4 col tiles of 128
    int bt = (bid >> 2) & 1;   // 2 row tiles of 256
    int i = bid >> 3;          // 50
    __shared__ float As[48 * 256];  // 48 KiB, k-major, XOR-swizzled 4-float groups
    __shared__ float Bs[48 * 128];  // 24 KiB
    int t = threadIdx.x;
    int tx = t & 15, ty = t >> 4;  // ty 0..31
    float acc[8][8];
#pragma unroll
    for (int r = 0; r < 8; ++r)
#pragma unroll
        for (int c = 0; c < 8; ++c) acc[r][c] = 0.f;

    // ---- load half-0 into regs ----
    float4 ra[6], rb[3];
#pragma unroll
    for (int u = 0; u < 6; ++u) {
        int idx = t + 512 * u;
        int r = idx / 12, c4 = (idx % 12) * 4;
        int b = bt * 256 + r;
        ra[u] = make_float4(0.f, 0.f, 0.f, 0.f);
        if (b < NGRAPH)
            ra[u] = *reinterpret_cast<const float4*>(pooled + ((size_t)b * KP + i) * 96 + c4);
    }
#pragma unroll
    for (int u = 0; u < 3; ++u) {
        int idx = t + 512 * u;
        int c = idx / 12, c4 = (idx % 12) * 4;
        int col = ct * 128 + c;
        rb[u] = *reinterpret_cast<const float4*>(
            Wc1 + (((size_t)(col >> 5) * KP + i) * 32 + (col & 31)) * 96 + c4);
    }
    // ---- write half-0 to LDS ----
#pragma unroll
    for (int u = 0; u < 6; ++u) {
        int idx = t + 512 * u;
        int r = idx / 12, c4 = (idx % 12) * 4;
        float vv[4] = {ra[u].x, ra[u].y, ra[u].z, ra[u].w};
#pragma unroll
        for (int j = 0; j < 4; ++j) {
            int k = c4 + j;
            int gp = (r >> 2) ^ ((k >> 2) & 31);
            As[k * 256 + gp * 4 + (r & 3)] = vv[j];
        }
    }
#pragma unroll
    for (int u = 0; u < 3; ++u) {
        int idx = t + 512 * u;
        int c = idx / 12, c4 = (idx % 12) * 4;
        float vv[4] = {rb[u].x, rb[u].y, rb[u].z, rb[u].w};
#pragma unroll
        for (int j = 0; j < 4; ++j) {
            int k = c4 + j;
            int gp = (c >> 2) ^ ((k >> 2) & 31);
            Bs[k * 128 + gp * 4 + (c & 3)] = vv[j];
        }
    }
    __syncthreads();
    // ---- prefetch half-1 into regs (hidden under half-0 compute) ----
    float4 ra2[6], rb2[3];
#pragma unroll
    for (int u = 0; u < 6; ++u) {
        int idx = t + 512 * u;
        int r = idx / 12, c4 = (idx % 12) * 4;
        int b = bt * 256 + r;
        ra2[u] = make_float4(0.f, 0.f, 0.f, 0.f);
        if (b < NGRAPH)
            ra2[u] = *reinterpret_cast<const float4*>(pooled + ((size_t)b * KP + i) * 96 + 48 + c4);
    }
#pragma unroll
    for (int u = 0; u < 3; ++u) {
        int idx = t + 512 * u;
        int c = idx / 12, c4 = (idx % 12) * 4;
        int col = ct * 128 + c;
        rb2[u] = *reinterpret_cast<const float4*>(
            Wc1 + (((size_t)(col >> 5) * KP + i) * 32 + (col & 31)) * 96 + 48 + c4);
    }
    // ---- compute half-0 ----
    for (int k = 0; k < 48; ++k) {
        int key = (k >> 2) & 31;
        float4 a0 = *reinterpret_cast<const float4*>(&As[k * 256 + 4 * (ty ^ key)]);
        float4 a1 = *reinterpret_cast<const float4*>(&As[k * 256 + 4 * ((32 + ty) ^ key)]);
        float4 b0 = *reinterpret_cast<const float4*>(&Bs[k * 128 + 4 * (tx ^ key)]);
        float4 b1 = *reinterpret_cast<const float4*>(&Bs[k * 128 + 4 * ((16 + tx) ^ key)]);
        float a[8] = {a0.x, a0.y, a0.z, a0.w, a1.x, a1.y, a1.z, a1.w};
        float bb[8] = {b0.x, b0.y, b0.z, b0.w, b1.x, b1.y, b1.z, b1.w};
#pragma unroll
        for (int r = 0; r < 8; ++r)
#pragma unroll
            for (int c = 0; c < 8; ++c) acc[r][c] += a[r] * bb[c];
    }
    __syncthreads();
    // ---- write half-1 to LDS ----
#pragma unroll
    for (int u = 0; u < 6; ++u) {
        int idx = t + 512 * u;
        int r = idx / 12, c4 = (idx % 12) * 4;
        float vv[4] = {ra2[u].x, ra2[u].y, ra2[u].z, ra2[u].w};
#pragma unroll
        for (int j = 0; j < 4; ++j) {
            int k = c4 + j;
            int gp = (r >> 2) ^ ((k >> 2) & 31);
            As[k * 256 + gp * 4 + (r & 3)] = vv[j];
        }
    }
#pragma unroll
    for (int u = 0; u < 3; ++u) {
        int idx = t + 512 * u;
        int c = idx / 12, c4 = (idx % 12) * 4;
        float vv[4] = {rb2[u].x, rb2[u].y, rb2[u].z, rb2[u].w};
#pragma unroll
        for (int j = 0; j < 4; ++j) {
            int k = c4 + j;
            int gp = (c >> 2) ^ ((k >> 2) & 31);
            Bs[k * 128 + gp * 4 + (c & 3)] = vv[j];
        }
    }
    __syncthreads();
    // ---- compute half-1 ----
    for (int k = 0; k < 48; ++k) {
        int key = (k >> 2) & 31;
        float4 a0 = *reinterpret_cast<const float4*>(&As[k * 256 + 4 * (ty ^ key)]);
        float4 a1 = *reinterpret_cast<const float4*>(&As[k * 256 + 4 * ((32 + ty) ^ key)]);
        float4 b0 = *reinterpret_cast<const float4*>(&Bs[k * 128 + 4 * (tx ^ key)]);
        float4 b1 = *reinterpret_cast<const float4*>(&Bs[k * 128 + 4 * ((16 + tx) ^ key)]);
        float a[8] = {a0.x, a0.y, a0.z, a0.w, a1.x, a1.y, a1.z, a1.w};
        float bb[8] = {b0.x, b0.y, b0.z, b0.w, b1.x, b1.y, b1.z, b1.w};
#pragma unroll
        for (int r = 0; r < 8; ++r)
#pragma unroll
            for (int c = 0; c < 8; ++c) acc[r][c] += a[r] * bb[c];
    }
#pragma unroll
    for (int rh = 0; rh < 2; ++rh)
#pragma unroll
        for (int rr = 0; rr < 4; ++rr) {
            int b = bt * 256 + rh * 128 + ty * 4 + rr;
            if (b >= NGRAPH) continue;
#pragma unroll
            for (int ch = 0; ch < 2; ++ch) {
                int col = ct * 128 + ch * 64 + tx * 4;
                int o = col >> 5, L = col & 31;
                float4 v = make_float4(acc[rh * 4 + rr][ch * 4 + 0],
                                       acc[rh * 4 + rr][ch * 4 + 1],
                                       acc[rh * 4 + rr][ch * 4 + 2],
                                       acc[rh * 4 + rr][ch * 4 + 3]);
                *reinterpret_cast<float4*>(priors + (((size_t)b * 16 + o) * KP + i) * 32 + L) = v;
            }
        }
}

// ---------------- fused capsule routing-1 + capsule-2 (per graph) ----------------
__global__ __launch_bounds__(256) void k_caps(const float* __restrict__ priors_g,
                                              const float* __restrict__ Wc2,
                                              float* __restrict__ out) {
    int b = blockIdx.x;
    __shared__ float P[16 * KP * 33];
    __shared__ float logits[16 * KP];
    __shared__ float c[16 * KP];
    __shared__ float s[16 * 32];
    __shared__ float v[16 * 32];
    __shared__ float scale[16];
    __shared__ float P2[NCLS * 16 * 17];
    __shared__ float logits2[NCLS * 16];
    __shared__ float c2[NCLS * 16];
    __shared__ float s2[NCLS * 16];
    __shared__ float v2[NCLS * 16];
    __shared__ float scale2[NCLS];
    int t = threadIdx.x;
    const float* pg = priors_g + (size_t)b * (16 * KP * 32);
    for (int idx = t; idx < 16 * KP * 32; idx += 256)
        P[(idx >> 5) * 33 + (idx & 31)] = pg[idx];
    for (int idx = t; idx < 16 * KP; idx += 256) logits[idx] = 0.f;
    __syncthreads();
    for (int it = 0; it < 3; ++it) {
        if (t < KP) {
            float m = -1e30f;
            for (int o = 0; o < 16; ++o) m = fmaxf(m, logits[o * KP + t]);
            float sum = 0.f;
            for (int o = 0; o < 16; ++o) {
                float e = expf(logits[o * KP + t] - m);
                c[o * KP + t] = e;
                sum += e;
            }
            for (int o = 0; o < 16; ++o) c[o * KP + t] /= sum;
        }
        __syncthreads();
        for (int idx = t; idx < 16 * 32; idx += 256) {
            int o = idx >> 5, L = idx & 31;
            float acc = 0.f;
            for (int i = 0; i < KP; ++i) acc += c[o * KP + i] * P[(o * KP + i) * 33 + L];
            s[idx] = acc;
        }
        __syncthreads();
        if (t < 16) {
            float sq = 0.f;
            for (int L = 0; L < 32; ++L) sq += s[t * 32 + L] * s[t * 32 + L];
            scale[t] = (sq / (1.f + sq)) * (1.0f / sqrtf(sq + 1e-12f));
        }
        __syncthreads();
        for (int idx = t; idx < 16 * 32; idx += 256) v[idx] = s[idx] * scale[idx >> 5];
        __syncthreads();
        if (it < 2) {
            for (int idx = t; idx < 16 * KP; idx += 256) {
                int o = idx / KP, i = idx % KP;
                float acc = 0.f;
                for (int L = 0; L < 32; ++L) acc += P[(o * KP + i) * 33 + L] * v[o * 32 + L];
                logits[idx] += acc;
            }
            __syncthreads();
        }
    }
    // ---- capsule-2: priors from v (in LDS) ----
    for (int idx = t; idx < NCLS * 16; idx += 256) logits2[idx] = 0.f;
    for (int idx = t; idx < NCLS * 16 * 16; idx += 256) {
        int L = idx & 15, i = (idx >> 4) & 15, o = idx >> 8;
        const float4* wr = reinterpret_cast<const float4*>(Wc2 + ((size_t)((o * 16 + i) * 16 + L)) * 32);
        const float4* ur = reinterpret_cast<const float4*>(&v[i * 32]);
        float acc = 0.f;
#pragma unroll
        for (int l = 0; l < 8; ++l) {
            float4 w4 = wr[l], u4 = ur[l];
            acc += w4.x * u4.x + w4.y * u4.y + w4.z * u4.z + w4.w * u4.w;
        }
        P2[(idx >> 4) * 17 + L] = acc;
    }
    __syncthreads();
    for (int it = 0; it < 3; ++it) {
        if (t < 16) {
            float m = -1e30f;
            for (int o = 0; o < NCLS; ++o) m = fmaxf(m, logits2[o * 16 + t]);
            float sum = 0.f;
            for (int o = 0; o < NCLS; ++o) {
                float e = expf(logits2[o * 16 + t] - m);
                c2[o * 16 + t] = e;
                sum += e;
            }
            for (int o = 0; o < NCLS; ++o) c2[o * 16 + t] /= sum;
        }
        __syncthreads();
        if (t < NCLS * 16) {
            int o = t >> 4, L = t & 15;
            float acc = 0.f;
            for (int i = 0; i < 16; ++i) acc += c2[o * 16 + i] * P2[(o * 16 + i) * 17 + L];
            s2[t] = acc;
        }
        __syncthreads();
        if (t < NCLS) {
            float sq = 0.f;
            for (int L = 0; L < 16; ++L) sq += s2[t * 16 + L] * s2[t * 16 + L];
            scale2[t] = (sq / (1.f + sq)) * (1.0f / sqrtf(sq + 1e-12f));
        }
        __syncthreads();
        if (t < NCLS * 16) v2[t] = s2[t] * scale2[t >> 4];
        __syncthreads();
        if (it < 2) {
            if (t < NCLS * 16) {
                int o = t >> 4, i = t & 15;
                float acc = 0.f;
                for (int L = 0; L < 16; ++L) acc += P2[(o * 16 + i) * 17 + L] * v2[o * 16 + L];
                logits2[t] += acc;
            }
            __syncthreads();
        }
    }
    if (t < NCLS) {
        float sq = 0.f;
        for (int L = 0; L < 16; ++L) sq += v2[t * 16 + L] * v2[t * 16 + L];
        out[(size_t)b * NCLS + t] = sqrtf(sq);
    }
}

extern "C" void kernel_launch(void* const* d_in, const int* in_sizes, int n_in,
                              void* d_out, int out_size, void* d_ws, size_t ws_size,
                              hipStream_t stream) {
    const float* x   = (const float*)d_in[0];
    const int*   ei  = (const int*)d_in[1];
    const float* W1  = (const float*)d_in[3];
    const float* b1  = (const float*)d_in[4];
    const float* W2  = (const float*)d_in[5];
    const float* b2  = (const float*)d_in[6];
    const float* W3  = (const float*)d_in[7];
    const float* b3  = (const float*)d_in[8];
    const float* Wc1 = (const float*)d_in[9];
    const float* Wc2 = (const float*)d_in[10];
    float* out = (float*)d_out;
    float* wsf = (float*)d_ws;

    const int* src = ei;
    const int* dst = ei + NEDGES;

    // ---- workspace layout (float-element offsets) ----
    float* xc = wsf;                                // 9,600,000
    float* R  = wsf + 9600000;
    int*   cursor  = (int*)R;                       // 196 (pad to 256)
    float* dinv    = R + 256;                       // 100,000
    int2*  begend  = (int2*)(R + 100256);           // 100,000 int2 = 200,000
    float* A       = R + 300256;                    // shared region: csorted | h | pooled
    unsigned* csorted = (unsigned*)A;               // NB1*CAP = 3,411,968
    float* h       = A;                             // 3,200,000 (after fill2, csorted dead)
    float* pooled  = A;                             // 2,400,000 (after gather3, h dead)
    int*   csrc    = (int*)(R + 3712224);           // 3,411,968 (bucket-strided)
    float* pr1     = R + 7124192;                   // 12,800,000

    // ---- CSR build: single-pass bucketed placement (fixed capacity) ----
    hipMemsetAsync(cursor, 0, 256 * sizeof(int), stream);
    k_place1<<<NBLK1, 512, 0, stream>>>(src, dst, cursor, csorted);
    k_fill2<<<NB1, 512, 0, stream>>>(cursor, csorted, csrc, begend, dinv);

    // ---- layer 1 ----
    k_matmul<<<(NNODES + 255) / 256, 256, 0, stream>>>(x, FIN, FIN, W1, dinv, h);
    k_gather<<<NNODES / 8, 256, 0, stream>>>(begend, csrc, dinv, h, b1, xc, 0);
    // ---- layer 2 ----
    k_matmul<<<(NNODES + 255) / 256, 256, 0, stream>>>(xc, 96, HID, W2, dinv, h);
    k_gather<<<NNODES / 8, 256, 0, stream>>>(begend, csrc, dinv, h, b2, xc, 32);
    // ---- layer 3 ----
    k_matmul<<<(NNODES + 255) / 256, 256, 0, stream>>>(xc + 32, 96, HID, W3, dinv, h);
    k_gather<<<NNODES / 8, 256, 0, stream>>>(begend, csrc, dinv, h, b3, xc, 64);

    // ---- sort-pool + capsules ----
    k_sortpool<<<NGRAPH, 256, 0, stream>>>(xc, pooled);
    k_priors1<<<KP * 8, 512, 0, stream>>>(pooled, Wc1, pr1);
    k_caps<<<NGRAPH, 256, 0, stream>>>(pr1, Wc2, out);
}

// Round 17
// 374.758 us; speedup vs baseline: 1.0036x; 1.0036x over previous
//
#include <hip/hip_runtime.h>

#define NNODES 100000
#define NEDGES 3200000
#define NPG 200
#define NGRAPH 500
#define FIN 128
#define HID 32
#define KP 50
#define NCLS 10

#define NB1 196      // ceil(100000/512) dst-buckets
#define BSH 9
#define CHUNK 8192
#define NBLK1 391    // ceil(NEDGES/CHUNK)
#define CAP 17408    // per-bucket slot capacity (mean 16384 + 8 sigma)

// ---------------- level-1 place: LDS-binned partition, direct bucket reservation ----------------
__global__ __launch_bounds__(512) void k_place1(const int* __restrict__ src,
                                                const int* __restrict__ dst,
                                                int* __restrict__ cursor,
                                                unsigned* __restrict__ csorted) {
    __shared__ int hist[NB1];
    __shared__ int lstart[NB1];
    __shared__ int base[NB1];
    __shared__ int cnt2[NB1];
    __shared__ int sarr[256];
    __shared__ unsigned buf[CHUNK];
    __shared__ int dbuf[CHUNK];
    int t = threadIdx.x;
    for (int i = t; i < NB1; i += 512) { hist[i] = 0; cnt2[i] = 0; }
    __syncthreads();
    int eb = blockIdx.x * CHUNK;
    for (int i = 0; i < CHUNK / 512; ++i) {
        int e = eb + t + i * 512;
        if (e < NEDGES) {
            int s = src[e], d = dst[e];
            if (s != d) atomicAdd(&hist[d >> BSH], 1);
        }
    }
    __syncthreads();
    if (t < 256) sarr[t] = (t < NB1) ? hist[t] : 0;
    __syncthreads();
    for (int ofs = 1; ofs < 256; ofs <<= 1) {
        int add = (t < 256 && t >= ofs) ? sarr[t - ofs] : 0;
        __syncthreads();
        if (t < 256) sarr[t] += add;
        __syncthreads();
    }
    if (t < NB1) {
        lstart[t] = (t == 0) ? 0 : sarr[t - 1];
        base[t] = hist[t] ? (t * CAP + atomicAdd(&cursor[t], hist[t])) : 0;
    }
    __syncthreads();
    for (int i = 0; i < CHUNK / 512; ++i) {
        int e = eb + t + i * 512;
        if (e < NEDGES) {
            int s = src[e], d = dst[e];
            if (s != d) {
                int bk = d >> BSH;
                int pos = atomicAdd(&cnt2[bk], 1);
                int slot = lstart[bk] + pos;
                buf[slot] = ((unsigned)s << BSH) | (unsigned)(d & 511);
                dbuf[slot] = base[bk] + pos;
            }
        }
    }
    __syncthreads();
    int nval = sarr[NB1 - 1];
    for (int j = t; j < nval; j += 512) csorted[dbuf[j]] = buf[j];
}

// ---------------- level-2: per-bucket CSR finalize (+begend, +dinv) ----------------
__global__ __launch_bounds__(512) void k_fill2(const int* __restrict__ cursor,
                                               const unsigned* __restrict__ csorted,
                                               int* __restrict__ csrc,
                                               int2* __restrict__ begend,
                                               float* __restrict__ dinv) {
    __shared__ int cnt[512];
    __shared__ int loffs[512];
    __shared__ int cnt2[512];
    __shared__ int sarr[512];
    int b = blockIdx.x, t = threadIdx.x;
    cnt[t] = 0; cnt2[t] = 0;
    __syncthreads();
    int base = b * CAP;
    int m = cursor[b];
    for (int j = t; j < m; j += 512) atomicAdd(&cnt[csorted[base + j] & 511], 1);
    __syncthreads();
    sarr[t] = cnt[t];
    __syncthreads();
    for (int ofs = 1; ofs < 512; ofs <<= 1) {
        int add = (t >= ofs) ? sarr[t - ofs] : 0;
        __syncthreads();
        sarr[t] += add;
        __syncthreads();
    }
    loffs[t] = sarr[t] - cnt[t];  // exclusive
    __syncthreads();
    int n = b * 512 + t;
    if (n < NNODES) {
        int beg = base + loffs[t];
        begend[n] = make_int2(beg, beg + cnt[t]);
        dinv[n] = rsqrtf((float)cnt[t] + 1.0f);
    }
    for (int j = t; j < m; j += 512) {
        unsigned p = csorted[base + j];
        int d = p & 511;
        int pos = atomicAdd(&cnt2[d], 1);
        csrc[base + loffs[d] + pos] = (int)(p >> BSH);
    }
}

// ---------------- hw = (X @ W) * dinv : 256 rows/block, thread = 8 rows x 4 cols ----------------
__global__ __launch_bounds__(256) void k_matmul(const float* __restrict__ X, int ldx, int K,
                                                const float* __restrict__ W,
                                                const float* __restrict__ dinv,
                                                float* __restrict__ h) {
    __shared__ float Xk[32 * 256];  // k-major slab, 32 KB
    __shared__ float Wl[32 * 36];   // padded, 4.6 KB
    int t = threadIdx.x;
    int tx = t & 7;    // col quad: cols 4tx..4tx+3
    int ty = t >> 3;   // 0..31: row quads ty and 32+ty
    int n0 = blockIdx.x * 256;
    float acc[8][4];
#pragma unroll
    for (int r = 0; r < 8; ++r)
#pragma unroll
        for (int c = 0; c < 4; ++c) acc[r][c] = 0.f;

    int ksteps = K >> 5;
    for (int ks = 0; ks < ksteps; ++ks) {
        int kbase = ks << 5;
        __syncthreads();
        for (int idx = t; idx < 256 * 8; idx += 256) {
            int row = idx >> 3, c4 = (idx & 7) * 4;
            float4 v = make_float4(0.f, 0.f, 0.f, 0.f);
            if (n0 + row < NNODES)
                v = *reinterpret_cast<const float4*>(X + (size_t)(n0 + row) * ldx + kbase + c4);
            float vv[4] = {v.x, v.y, v.z, v.w};
#pragma unroll
            for (int j = 0; j < 4; ++j) {
                int k = c4 + j;
                int gp = (row >> 2) ^ ((k >> 2) & 31);
                Xk[k * 256 + gp * 4 + (row & 3)] = vv[j];
            }
        }
        for (int idx = t; idx < 32 * 32; idx += 256) {
            int k = idx >> 5, j = idx & 31;
            Wl[k * 36 + j] = W[(size_t)(kbase + k) * HID + j];
        }
        __syncthreads();
        const float4* Xq = reinterpret_cast<const float4*>(Xk);
        const float4* Wq = reinterpret_cast<const float4*>(Wl);
        for (int k = 0; k < 32; ++k) {
            int key = (k >> 2) & 31;
            float4 a0 = Xq[k * 64 + (ty ^ key)];
            float4 a1 = Xq[k * 64 + 32 + (ty ^ key)];
            float4 wv = Wq[k * 9 + tx];
            float a[8] = {a0.x, a0.y, a0.z, a0.w, a1.x, a1.y, a1.z, a1.w};
#pragma unroll
            for (int r = 0; r < 8; ++r) {
                acc[r][0] += a[r] * wv.x;
                acc[r][1] += a[r] * wv.y;
                acc[r][2] += a[r] * wv.z;
                acc[r][3] += a[r] * wv.w;
            }
        }
    }
#pragma unroll
    for (int r = 0; r < 8; ++r) {
        int row = (r < 4) ? (4 * ty + r) : (128 + 4 * ty + (r - 4));
        int gr = n0 + row;
        if (gr < NNODES) {
            float di = dinv[gr];
            float4 v = make_float4(acc[r][0] * di, acc[r][1] * di, acc[r][2] * di, acc[r][3] * di);
            *reinterpret_cast<float4*>(h + (size_t)gr * HID + 4 * tx) = v;
        }
    }
}

// ---------------- gather: 2 nodes/wave, 8-deep unroll, unmasked fast path ----------------
__global__ __launch_bounds__(256) void k_gather(const int2* __restrict__ begend,
                                                const int* __restrict__ csrc,
                                                const float* __restrict__ dinv,
                                                const float* __restrict__ hw,
                                                const float* __restrict__ bias,
                                                float* __restrict__ xc, int coloff) {
    int t = threadIdx.x;
    int wv = t >> 6;
    int lane = t & 63;
    int nh = lane >> 5;    // node half within wave
    int sub = lane & 31;
    int g = sub >> 3;      // edge slot 0..3
    int q = sub & 7;       // channel quad 0..7
    int n = blockIdx.x * 8 + wv * 2 + nh;
    int2 be = begend[n];
    int beg = be.x, end = be.y, last = end - 1;
    float4 acc = make_float4(0.f, 0.f, 0.f, 0.f);
    int e0 = beg + g;
    for (; e0 + 28 < end; e0 += 32) {
#pragma unroll
        for (int j = 0; j < 8; ++j) {
            int s = csrc[e0 + 4 * j];
            float4 hv = *reinterpret_cast<const float4*>(hw + (size_t)s * HID + q * 4);
            acc.x += hv.x; acc.y += hv.y; acc.z += hv.z; acc.w += hv.w;
        }
    }
    if (e0 < end) {
#pragma unroll
        for (int j = 0; j < 8; ++j) {
            int e = e0 + 4 * j;
            float mk = (e <= last) ? 1.f : 0.f;
            int s = csrc[min(e, last)];
            float4 hv = *reinterpret_cast<const float4*>(hw + (size_t)s * HID + q * 4);
            acc.x += mk * hv.x; acc.y += mk * hv.y; acc.z += mk * hv.z; acc.w += mk * hv.w;
        }
    }
    for (int m = 8; m <= 16; m <<= 1) {
        acc.x += __shfl_xor(acc.x, m, 64);
        acc.y += __shfl_xor(acc.y, m, 64);
        acc.z += __shfl_xor(acc.z, m, 64);
        acc.w += __shfl_xor(acc.w, m, 64);
    }
    if (g == 0) {
        float di = dinv[n];
        float4 hv = *reinterpret_cast<const float4*>(hw + (size_t)n * HID + q * 4);
        float4 bv = *reinterpret_cast<const float4*>(bias + q * 4);
        float4 v;
        v.x = tanhf(di * (acc.x + hv.x) + bv.x);
        v.y = tanhf(di * (acc.y + hv.y) + bv.y);
        v.z = tanhf(di * (acc.z + hv.z) + bv.z);
        v.w = tanhf(di * (acc.w + hv.w) + bv.w);
        *reinterpret_cast<float4*>(xc + (size_t)n * 96 + coloff + q * 4) = v;
    }
}

// ---------------- stable top-50 sort-pool per graph ----------------
__global__ __launch_bounds__(256) void k_sortpool(const float* __restrict__ xc,
                                                  float* __restrict__ pooled) {
    int g = blockIdx.x;
    __shared__ float vals[NPG];
    __shared__ int sel[KP];
    int t = threadIdx.x;
    if (t < NPG) vals[t] = xc[((size_t)g * NPG + t) * 96 + 95];
    __syncthreads();
    if (t < NPG) {
        float v = vals[t];
        int r = 0;
        for (int k = 0; k < NPG; ++k) {
            float vk = vals[k];
            r += (vk > v) || (vk == v && k < t);
        }
        if (r < KP) sel[r] = t;
    }
    __syncthreads();
    for (int idx = t; idx < KP * 24; idx += 256) {
        int r = idx / 24, c4 = (idx % 24) * 4;
        *reinterpret_cast<float4*>(pooled + (size_t)g * KP * 96 + r * 96 + c4) =
            *reinterpret_cast<const float4*>(xc + ((size_t)g * NPG + sel[r]) * 96 + c4);
    }
}

// ---------------- capsule-1 priors: 256x128 tile, 512 thr, 8x8/thread, reg-prefetch ----------------
__global__ __launch_bounds__(512, 2) void k_priors1(const float* __restrict__ pooled,
                                                    const float* __restrict__ Wc1,
                                                    float* __restrict__ priors) {
    int bid = blockIdx.x;
    int ct = bid & 3;          // 4 col tiles of 128
    int bt = (bid >> 2) & 1;   // 2 row tiles of 256
    int i = bid >> 3;          // 50
    __shared__ float As[48 * 256];  // 48 KiB, k-major, XOR-swizzled 4-float groups
    __shared__ float Bs[48 * 128];  // 24 KiB
    int t = threadIdx.x;
    int tx = t & 15, ty = t >> 4;  // ty 0..31
    float acc[8][8];
#pragma unroll
    for (int r = 0; r < 8; ++r)
#pragma unroll
        for (int c = 0; c < 8; ++c) acc[r][c] = 0.f;

    // ---- load half-0 into regs ----
    float4 ra[6], rb[3];
#pragma unroll
    for (int u = 0; u < 6; ++u) {
        int idx = t + 512 * u;
        int r = idx / 12, c4 = (idx % 12) * 4;
        int b = bt * 256 + r;
        ra[u] = make_float4(0.f, 0.f, 0.f, 0.f);
        if (b < NGRAPH)
            ra[u] = *reinterpret_cast<const float4*>(pooled + ((size_t)b * KP + i) * 96 + c4);
    }
#pragma unroll
    for (int u = 0; u < 3; ++u) {
        int idx = t + 512 * u;
        int c = idx / 12, c4 = (idx % 12) * 4;
        int col = ct * 128 + c;
        rb[u] = *reinterpret_cast<const float4*>(
            Wc1 + (((size_t)(col >> 5) * KP + i) * 32 + (col & 31)) * 96 + c4);
    }
    // ---- write half-0 to LDS ----
#pragma unroll
    for (int u = 0; u < 6; ++u) {
        int idx = t + 512 * u;
        int r = idx / 12, c4 = (idx % 12) * 4;
        float vv[4] = {ra[u].x, ra[u].y, ra[u].z, ra[u].w};
#pragma unroll
        for (int j = 0; j < 4; ++j) {
            int k = c4 + j;
            int gp = (r >> 2) ^ ((k >> 2) & 31);
            As[k * 256 + gp * 4 + (r & 3)] = vv[j];
        }
    }
#pragma unroll
    for (int u = 0; u < 3; ++u) {
        int idx = t + 512 * u;
        int c = idx / 12, c4 = (idx % 12) * 4;
        float vv[4] = {rb[u].x, rb[u].y, rb[u].z, rb[u].w};
#pragma unroll
        for (int j = 0; j < 4; ++j) {
            int k = c4 + j;
            int gp = (c >> 2) ^ ((k >> 2) & 31);
            Bs[k * 128 + gp * 4 + (c & 3)] = vv[j];
        }
    }
    __syncthreads();
    // ---- prefetch half-1 into regs (hidden under half-0 compute) ----
    float4 ra2[6], rb2[3];
#pragma unroll
    for (int u = 0; u < 6; ++u) {
        int idx = t + 512 * u;
        int r = idx / 12, c4 = (idx % 12) * 4;
        int b = bt * 256 + r;
        ra2[u] = make_float4(0.f, 0.f, 0.f, 0.f);
        if (b < NGRAPH)
            ra2[u] = *reinterpret_cast<const float4*>(pooled + ((size_t)b * KP + i) * 96 + 48 + c4);
    }
#pragma unroll
    for (int u = 0; u < 3; ++u) {
        int idx = t + 512 * u;
        int c = idx / 12, c4 = (idx % 12) * 4;
        int col = ct * 128 + c;
        rb2[u] = *reinterpret_cast<const float4*>(
            Wc1 + (((size_t)(col >> 5) * KP + i) * 32 + (col & 31)) * 96 + 48 + c4);
    }
    // ---- compute half-0 ----
    for (int k = 0; k < 48; ++k) {
        int key = (k >> 2) & 31;
        float4 a0 = *reinterpret_cast<const float4*>(&As[k * 256 + 4 * (ty ^ key)]);
        float4 a1 = *reinterpret_cast<const float4*>(&As[k * 256 + 4 * ((32 + ty) ^ key)]);
        float4 b0 = *reinterpret_cast<const float4*>(&Bs[k * 128 + 4 * (tx ^ key)]);
        float4 b1 = *reinterpret_cast<const float4*>(&Bs[k * 128 + 4 * ((16 + tx) ^ key)]);
        float a[8] = {a0.x, a0.y, a0.z, a0.w, a1.x, a1.y, a1.z, a1.w};
        float bb[8] = {b0.x, b0.y, b0.z, b0.w, b1.x, b1.y, b1.z, b1.w};
#pragma unroll
        for (int r = 0; r < 8; ++r)
#pragma unroll
            for (int c = 0; c < 8; ++c) acc[r][c] += a[r] * bb[c];
    }
    __syncthreads();
    // ---- write half-1 to LDS ----
#pragma unroll
    for (int u = 0; u < 6; ++u) {
        int idx = t + 512 * u;
        int r = idx / 12, c4 = (idx % 12) * 4;
        float vv[4] = {ra2[u].x, ra2[u].y, ra2[u].z, ra2[u].w};
#pragma unroll
        for (int j = 0; j < 4; ++j) {
            int k = c4 + j;
            int gp = (r >> 2) ^ ((k >> 2) & 31);
            As[k * 256 + gp * 4 + (r & 3)] = vv[j];
        }
    }
#pragma unroll
    for (int u = 0; u < 3; ++u) {
        int idx = t + 512 * u;
        int c = idx / 12, c4 = (idx % 12) * 4;
        float vv[4] = {rb2[u].x, rb2[u].y, rb2[u].z, rb2[u].w};
#pragma unroll
        for (int j = 0; j < 4; ++j) {
            int k = c4 + j;
            int gp = (c >> 2) ^ ((k >> 2) & 31);
            Bs[k * 128 + gp * 4 + (c & 3)] = vv[j];
        }
    }
    __syncthreads();
    // ---- compute half-1 ----
    for (int k = 0; k < 48; ++k) {
        int key = (k >> 2) & 31;
        float4 a0 = *reinterpret_cast<const float4*>(&As[k * 256 + 4 * (ty ^ key)]);
        float4 a1 = *reinterpret_cast<const float4*>(&As[k * 256 + 4 * ((32 + ty) ^ key)]);
        float4 b0 = *reinterpret_cast<const float4*>(&Bs[k * 128 + 4 * (tx ^ key)]);
        float4 b1 = *reinterpret_cast<const float4*>(&Bs[k * 128 + 4 * ((16 + tx) ^ key)]);
        float a[8] = {a0.x, a0.y, a0.z, a0.w, a1.x, a1.y, a1.z, a1.w};
        float bb[8] = {b0.x, b0.y, b0.z, b0.w, b1.x, b1.y, b1.z, b1.w};
#pragma unroll
        for (int r = 0; r < 8; ++r)
#pragma unroll
            for (int c = 0; c < 8; ++c) acc[r][c] += a[r] * bb[c];
    }
#pragma unroll
    for (int rh = 0; rh < 2; ++rh)
#pragma unroll
        for (int rr = 0; rr < 4; ++rr) {
            int b = bt * 256 + rh * 128 + ty * 4 + rr;
            if (b >= NGRAPH) continue;
#pragma unroll
            for (int ch = 0; ch < 2; ++ch) {
                int col = ct * 128 + ch * 64 + tx * 4;
                int o = col >> 5, L = col & 31;
                float4 v = make_float4(acc[rh * 4 + rr][ch * 4 + 0],
                                       acc[rh * 4 + rr][ch * 4 + 1],
                                       acc[rh * 4 + rr][ch * 4 + 2],
                                       acc[rh * 4 + rr][ch * 4 + 3]);
                *reinterpret_cast<float4*>(priors + (((size_t)b * 16 + o) * KP + i) * 32 + L) = v;
            }
        }
}

// ---------------- capsule-1 routing (per graph, all in LDS) ----------------
__global__ __launch_bounds__(256) void k_routing1(const float* __restrict__ priors_g,
                                                  float* __restrict__ v_out) {
    int b = blockIdx.x;
    __shared__ float P[16 * KP * 33];
    __shared__ float logits[16 * KP];
    __shared__ float c[16 * KP];
    __shared__ float s[16 * 32];
    __shared__ float v[16 * 32];
    __shared__ float scale[16];
    int t = threadIdx.x;
    const float* pg = priors_g + (size_t)b * (16 * KP * 32);
    for (int idx = t; idx < 16 * KP * 32; idx += 256)
        P[(idx >> 5) * 33 + (idx & 31)] = pg[idx];
    for (int idx = t; idx < 16 * KP; idx += 256) logits[idx] = 0.f;
    __syncthreads();
    for (int it = 0; it < 3; ++it) {
        if (t < KP) {
            float m = -1e30f;
            for (int o = 0; o < 16; ++o) m = fmaxf(m, logits[o * KP + t]);
            float sum = 0.f;
            for (int o = 0; o < 16; ++o) {
                float e = expf(logits[o * KP + t] - m);
                c[o * KP + t] = e;
                sum += e;
            }
            for (int o = 0; o < 16; ++o) c[o * KP + t] /= sum;
        }
        __syncthreads();
        for (int idx = t; idx < 16 * 32; idx += 256) {
            int o = idx >> 5, L = idx & 31;
            float acc = 0.f;
            for (int i = 0; i < KP; ++i) acc += c[o * KP + i] * P[(o * KP + i) * 33 + L];
            s[idx] = acc;
        }
        __syncthreads();
        if (t < 16) {
            float sq = 0.f;
            for (int L = 0; L < 32; ++L) sq += s[t * 32 + L] * s[t * 32 + L];
            scale[t] = (sq / (1.f + sq)) * (1.0f / sqrtf(sq + 1e-12f));
        }
        __syncthreads();
        for (int idx = t; idx < 16 * 32; idx += 256) v[idx] = s[idx] * scale[idx >> 5];
        __syncthreads();
        if (it < 2) {
            for (int idx = t; idx < 16 * KP; idx += 256) {
                int o = idx / KP, i = idx % KP;
                float acc = 0.f;
                for (int L = 0; L < 32; ++L) acc += P[(o * KP + i) * 33 + L] * v[o * 32 + L];
                logits[idx] += acc;
            }
            __syncthreads();
        }
    }
    for (int idx = t; idx < 16 * 32; idx += 256) v_out[(size_t)b * 512 + idx] = v[idx];
}

// ---------------- capsule-2 fused: priors (into LDS) + routing + final norms ----------------
__global__ __launch_bounds__(256) void k_caps2(const float* __restrict__ v1,
                                               const float* __restrict__ Wc2,
                                               float* __restrict__ out) {
    int b = blockIdx.x;
    __shared__ float ul[16 * 32];
    __shared__ float P[NCLS * 16 * 17];
    __shared__ float logits[NCLS * 16];
    __shared__ float c[NCLS * 16];
    __shared__ float s[NCLS * 16];
    __shared__ float v[NCLS * 16];
    __shared__ float scale[NCLS];
    int t = threadIdx.x;
    for (int idx = t; idx < 512; idx += 256) ul[idx] = v1[(size_t)b * 512 + idx];
    for (int idx = t; idx < NCLS * 16; idx += 256) logits[idx] = 0.f;
    __syncthreads();
    for (int idx = t; idx < NCLS * 16 * 16; idx += 256) {
        int L = idx & 15, i = (idx >> 4) & 15, o = idx >> 8;
        const float4* wr = reinterpret_cast<const float4*>(Wc2 + ((size_t)((o * 16 + i) * 16 + L)) * 32);
        const float4* ur = reinterpret_cast<const float4*>(&ul[i * 32]);
        float acc = 0.f;
#pragma unroll
        for (int l = 0; l < 8; ++l) {
            float4 w4 = wr[l], u4 = ur[l];
            acc += w4.x * u4.x + w4.y * u4.y + w4.z * u4.z + w4.w * u4.w;
        }
        P[(idx >> 4) * 17 + L] = acc;
    }
    __syncthreads();
    for (int it = 0; it < 3; ++it) {
        if (t < 16) {
            float m = -1e30f;
            for (int o = 0; o < NCLS; ++o) m = fmaxf(m, logits[o * 16 + t]);
            float sum = 0.f;
            for (int o = 0; o < NCLS; ++o) {
                float e = expf(logits[o * 16 + t] - m);
                c[o * 16 + t] = e;
                sum += e;
            }
            for (int o = 0; o < NCLS; ++o) c[o * 16 + t] /= sum;
        }
        __syncthreads();
        if (t < NCLS * 16) {
            int o = t >> 4, L = t & 15;
            float acc = 0.f;
            for (int i = 0; i < 16; ++i) acc += c[o * 16 + i] * P[(o * 16 + i) * 17 + L];
            s[t] = acc;
        }
        __syncthreads();
        if (t < NCLS) {
            float sq = 0.f;
            for (int L = 0; L < 16; ++L) sq += s[t * 16 + L] * s[t * 16 + L];
            scale[t] = (sq / (1.f + sq)) * (1.0f / sqrtf(sq + 1e-12f));
        }
        __syncthreads();
        if (t < NCLS * 16) v[t] = s[t] * scale[t >> 4];
        __syncthreads();
        if (it < 2) {
            if (t < NCLS * 16) {
                int o = t >> 4, i = t & 15;
                float acc = 0.f;
                for (int L = 0; L < 16; ++L) acc += P[(o * 16 + i) * 17 + L] * v[o * 16 + L];
                logits[t] += acc;
            }
            __syncthreads();
        }
    }
    if (t < NCLS) {
        float sq = 0.f;
        for (int L = 0; L < 16; ++L) sq += v[t * 16 + L] * v[t * 16 + L];
        out[(size_t)b * NCLS + t] = sqrtf(sq);
    }
}

extern "C" void kernel_launch(void* const* d_in, const int* in_sizes, int n_in,
                              void* d_out, int out_size, void* d_ws, size_t ws_size,
                              hipStream_t stream) {
    const float* x   = (const float*)d_in[0];
    const int*   ei  = (const int*)d_in[1];
    const float* W1  = (const float*)d_in[3];
    const float* b1  = (const float*)d_in[4];
    const float* W2  = (const float*)d_in[5];
    const float* b2  = (const float*)d_in[6];
    const float* W3  = (const float*)d_in[7];
    const float* b3  = (const float*)d_in[8];
    const float* Wc1 = (const float*)d_in[9];
    const float* Wc2 = (const float*)d_in[10];
    float* out = (float*)d_out;
    float* wsf = (float*)d_ws;

    const int* src = ei;
    const int* dst = ei + NEDGES;

    // ---- workspace layout (float-element offsets) ----
    float* xc = wsf;                                // 9,600,000
    float* R  = wsf + 9600000;
    int*   cursor  = (int*)R;                       // 196 (pad to 256)
    float* dinv    = R + 256;                       // 100,000
    int2*  begend  = (int2*)(R + 100256);           // 100,000 int2 = 200,000
    float* A       = R + 300256;                    // shared region: csorted | h | pooled
    unsigned* csorted = (unsigned*)A;               // NB1*CAP = 3,411,968
    float* h       = A;                             // 3,200,000 (after fill2, csorted dead)
    float* pooled  = A;                             // 2,400,000 (after gather3, h dead)
    int*   csrc    = (int*)(R + 3712224);           // 3,411,968 (bucket-strided)
    float* pr1     = R + 7124192;                   // 12,800,000
    float* v1      = R + 19924192;                  // 256,000

    // ---- CSR build: single-pass bucketed placement (fixed capacity) ----
    hipMemsetAsync(cursor, 0, 256 * sizeof(int), stream);
    k_place1<<<NBLK1, 512, 0, stream>>>(src, dst, cursor, csorted);
    k_fill2<<<NB1, 512, 0, stream>>>(cursor, csorted, csrc, begend, dinv);

    // ---- layer 1 ----
    k_matmul<<<(NNODES + 255) / 256, 256, 0, stream>>>(x, FIN, FIN, W1, dinv, h);
    k_gather<<<NNODES / 8, 256, 0, stream>>>(begend, csrc, dinv, h, b1, xc, 0);
    // ---- layer 2 ----
    k_matmul<<<(NNODES + 255) / 256, 256, 0, stream>>>(xc, 96, HID, W2, dinv, h);
    k_gather<<<NNODES / 8, 256, 0, stream>>>(begend, csrc, dinv, h, b2, xc, 32);
    // ---- layer 3 ----
    k_matmul<<<(NNODES + 255) / 256, 256, 0, stream>>>(xc + 32, 96, HID, W3, dinv, h);
    k_gather<<<NNODES / 8, 256, 0, stream>>>(begend, csrc, dinv, h, b3, xc, 64);

    // ---- sort-pool + capsules ----
    k_sortpool<<<NGRAPH, 256, 0, stream>>>(xc, pooled);
    k_priors1<<<KP * 8, 512, 0, stream>>>(pooled, Wc1, pr1);
    k_routing1<<<NGRAPH, 256, 0, stream>>>(pr1, v1);
    k_caps2<<<NGRAPH, 256, 0, stream>>>(v1, Wc2, out);
}

// Round 18
// 371.624 us; speedup vs baseline: 1.0120x; 1.0084x over previous
//
#include <hip/hip_runtime.h>

#define NNODES 100000
#define NEDGES 3200000
#define NPG 200
#define NGRAPH 500
#define FIN 128
#define HID 32
#define KP 50
#define NCLS 10

#define NB1 196      // ceil(100000/512) dst-buckets
#define BSH 9
#define CHUNK 8192
#define NBLK1 391    // ceil(NEDGES/CHUNK)
#define CAP 17408    // per-bucket slot capacity (mean 16384 + 8 sigma)

// ---------------- level-1 place: LDS-binned partition, direct bucket reservation ----------------
__global__ __launch_bounds__(512) void k_place1(const int* __restrict__ src,
                                                const int* __restrict__ dst,
                                                int* __restrict__ cursor,
                                                unsigned* __restrict__ csorted) {
    __shared__ int hist[NB1];
    __shared__ int lstart[NB1];
    __shared__ int base[NB1];
    __shared__ int cnt2[NB1];
    __shared__ int sarr[256];
    __shared__ unsigned buf[CHUNK];
    __shared__ int dbuf[CHUNK];
    int t = threadIdx.x;
    for (int i = t; i < NB1; i += 512) { hist[i] = 0; cnt2[i] = 0; }
    __syncthreads();
    int eb = blockIdx.x * CHUNK;
    for (int i = 0; i < CHUNK / 512; ++i) {
        int e = eb + t + i * 512;
        if (e < NEDGES) {
            int s = src[e], d = dst[e];
            if (s != d) atomicAdd(&hist[d >> BSH], 1);
        }
    }
    __syncthreads();
    if (t < 256) sarr[t] = (t < NB1) ? hist[t] : 0;
    __syncthreads();
    for (int ofs = 1; ofs < 256; ofs <<= 1) {
        int add = (t < 256 && t >= ofs) ? sarr[t - ofs] : 0;
        __syncthreads();
        if (t < 256) sarr[t] += add;
        __syncthreads();
    }
    if (t < NB1) {
        lstart[t] = (t == 0) ? 0 : sarr[t - 1];
        base[t] = hist[t] ? (t * CAP + atomicAdd(&cursor[t], hist[t])) : 0;
    }
    __syncthreads();
    for (int i = 0; i < CHUNK / 512; ++i) {
        int e = eb + t + i * 512;
        if (e < NEDGES) {
            int s = src[e], d = dst[e];
            if (s != d) {
                int bk = d >> BSH;
                int pos = atomicAdd(&cnt2[bk], 1);
                int slot = lstart[bk] + pos;
                buf[slot] = ((unsigned)s << BSH) | (unsigned)(d & 511);
                dbuf[slot] = base[bk] + pos;
            }
        }
    }
    __syncthreads();
    int nval = sarr[NB1 - 1];
    for (int j = t; j < nval; j += 512) csorted[dbuf[j]] = buf[j];
}

// ---------------- level-2: per-bucket CSR finalize (+begend, +dinv) ----------------
__global__ __launch_bounds__(512) void k_fill2(const int* __restrict__ cursor,
                                               const unsigned* __restrict__ csorted,
                                               int* __restrict__ csrc,
                                               int2* __restrict__ begend,
                                               float* __restrict__ dinv) {
    __shared__ int cnt[512];
    __shared__ int loffs[512];
    __shared__ int cnt2[512];
    __shared__ int sarr[512];
    int b = blockIdx.x, t = threadIdx.x;
    cnt[t] = 0; cnt2[t] = 0;
    __syncthreads();
    int base = b * CAP;
    int m = cursor[b];
    for (int j = t; j < m; j += 512) atomicAdd(&cnt[csorted[base + j] & 511], 1);
    __syncthreads();
    sarr[t] = cnt[t];
    __syncthreads();
    for (int ofs = 1; ofs < 512; ofs <<= 1) {
        int add = (t >= ofs) ? sarr[t - ofs] : 0;
        __syncthreads();
        sarr[t] += add;
        __syncthreads();
    }
    loffs[t] = sarr[t] - cnt[t];  // exclusive
    __syncthreads();
    int n = b * 512 + t;
    if (n < NNODES) {
        int beg = base + loffs[t];
        begend[n] = make_int2(beg, beg + cnt[t]);
        dinv[n] = rsqrtf((float)cnt[t] + 1.0f);
    }
    for (int j = t; j < m; j += 512) {
        unsigned p = csorted[base + j];
        int d = p & 511;
        int pos = atomicAdd(&cnt2[d], 1);
        csrc[base + loffs[d] + pos] = (int)(p >> BSH);
    }
}

// ---------------- hw = (X @ W) * dinv : 256 rows/block, thread = 8 rows x 4 cols ----------------
__global__ __launch_bounds__(256) void k_matmul(const float* __restrict__ X, int ldx, int K,
                                                const float* __restrict__ W,
                                                const float* __restrict__ dinv,
                                                float* __restrict__ h) {
    __shared__ float Xk[32 * 256];  // k-major slab, 32 KB
    __shared__ float Wl[32 * 36];   // padded, 4.6 KB
    int t = threadIdx.x;
    int tx = t & 7;    // col quad: cols 4tx..4tx+3
    int ty = t >> 3;   // 0..31: row quads ty and 32+ty
    int n0 = blockIdx.x * 256;
    float acc[8][4];
#pragma unroll
    for (int r = 0; r < 8; ++r)
#pragma unroll
        for (int c = 0; c < 4; ++c) acc[r][c] = 0.f;

    int ksteps = K >> 5;
    for (int ks = 0; ks < ksteps; ++ks) {
        int kbase = ks << 5;
        __syncthreads();
        for (int idx = t; idx < 256 * 8; idx += 256) {
            int row = idx >> 3, c4 = (idx & 7) * 4;
            float4 v = make_float4(0.f, 0.f, 0.f, 0.f);
            if (n0 + row < NNODES)
                v = *reinterpret_cast<const float4*>(X + (size_t)(n0 + row) * ldx + kbase + c4);
            float vv[4] = {v.x, v.y, v.z, v.w};
#pragma unroll
            for (int j = 0; j < 4; ++j) {
                int k = c4 + j;
                int gp = (row >> 2) ^ ((k >> 2) & 31);
                Xk[k * 256 + gp * 4 + (row & 3)] = vv[j];
            }
        }
        for (int idx = t; idx < 32 * 32; idx += 256) {
            int k = idx >> 5, j = idx & 31;
            Wl[k * 36 + j] = W[(size_t)(kbase + k) * HID + j];
        }
        __syncthreads();
        const float4* Xq = reinterpret_cast<const float4*>(Xk);
        const float4* Wq = reinterpret_cast<const float4*>(Wl);
        for (int k = 0; k < 32; ++k) {
            int key = (k >> 2) & 31;
            float4 a0 = Xq[k * 64 + (ty ^ key)];
            float4 a1 = Xq[k * 64 + 32 + (ty ^ key)];
            float4 wv = Wq[k * 9 + tx];
            float a[8] = {a0.x, a0.y, a0.z, a0.w, a1.x, a1.y, a1.z, a1.w};
#pragma unroll
            for (int r = 0; r < 8; ++r) {
                acc[r][0] += a[r] * wv.x;
                acc[r][1] += a[r] * wv.y;
                acc[r][2] += a[r] * wv.z;
                acc[r][3] += a[r] * wv.w;
            }
        }
    }
#pragma unroll
    for (int r = 0; r < 8; ++r) {
        int row = (r < 4) ? (4 * ty + r) : (128 + 4 * ty + (r - 4));
        int gr = n0 + row;
        if (gr < NNODES) {
            float di = dinv[gr];
            float4 v = make_float4(acc[r][0] * di, acc[r][1] * di, acc[r][2] * di, acc[r][3] * di);
            *reinterpret_cast<float4*>(h + (size_t)gr * HID + 4 * tx) = v;
        }
    }
}

// ---------------- gather: 2 nodes/wave, 8-deep unroll, unmasked fast path ----------------
__global__ __launch_bounds__(256) void k_gather(const int2* __restrict__ begend,
                                                const int* __restrict__ csrc,
                                                const float* __restrict__ dinv,
                                                const float* __restrict__ hw,
                                                const float* __restrict__ bias,
                                                float* __restrict__ xc, int coloff) {
    int t = threadIdx.x;
    int wv = t >> 6;
    int lane = t & 63;
    int nh = lane >> 5;    // node half within wave
    int sub = lane & 31;
    int g = sub >> 3;      // edge slot 0..3
    int q = sub & 7;       // channel quad 0..7
    int n = blockIdx.x * 8 + wv * 2 + nh;
    int2 be = begend[n];
    int beg = be.x, end = be.y, last = end - 1;
    float4 acc = make_float4(0.f, 0.f, 0.f, 0.f);
    int e0 = beg + g;
    for (; e0 + 28 < end; e0 += 32) {
#pragma unroll
        for (int j = 0; j < 8; ++j) {
            int s = csrc[e0 + 4 * j];
            float4 hv = *reinterpret_cast<const float4*>(hw + (size_t)s * HID + q * 4);
            acc.x += hv.x; acc.y += hv.y; acc.z += hv.z; acc.w += hv.w;
        }
    }
    if (e0 < end) {
#pragma unroll
        for (int j = 0; j < 8; ++j) {
            int e = e0 + 4 * j;
            float mk = (e <= last) ? 1.f : 0.f;
            int s = csrc[min(e, last)];
            float4 hv = *reinterpret_cast<const float4*>(hw + (size_t)s * HID + q * 4);
            acc.x += mk * hv.x; acc.y += mk * hv.y; acc.z += mk * hv.z; acc.w += mk * hv.w;
        }
    }
    for (int m = 8; m <= 16; m <<= 1) {
        acc.x += __shfl_xor(acc.x, m, 64);
        acc.y += __shfl_xor(acc.y, m, 64);
        acc.z += __shfl_xor(acc.z, m, 64);
        acc.w += __shfl_xor(acc.w, m, 64);
    }
    if (g == 0) {
        float di = dinv[n];
        float4 hv = *reinterpret_cast<const float4*>(hw + (size_t)n * HID + q * 4);
        float4 bv = *reinterpret_cast<const float4*>(bias + q * 4);
        float4 v;
        v.x = tanhf(di * (acc.x + hv.x) + bv.x);
        v.y = tanhf(di * (acc.y + hv.y) + bv.y);
        v.z = tanhf(di * (acc.z + hv.z) + bv.z);
        v.w = tanhf(di * (acc.w + hv.w) + bv.w);
        *reinterpret_cast<float4*>(xc + (size_t)n * 96 + coloff + q * 4) = v;
    }
}

// ---------------- stable top-50 sort-pool per graph ----------------
__global__ __launch_bounds__(256) void k_sortpool(const float* __restrict__ xc,
                                                  float* __restrict__ pooled) {
    int g = blockIdx.x;
    __shared__ float vals[NPG];
    __shared__ int sel[KP];
    int t = threadIdx.x;
    if (t < NPG) vals[t] = xc[((size_t)g * NPG + t) * 96 + 95];
    __syncthreads();
    if (t < NPG) {
        float v = vals[t];
        int r = 0;
        for (int k = 0; k < NPG; ++k) {
            float vk = vals[k];
            r += (vk > v) || (vk == v && k < t);
        }
        if (r < KP) sel[r] = t;
    }
    __syncthreads();
    for (int idx = t; idx < KP * 24; idx += 256) {
        int r = idx / 24, c4 = (idx % 24) * 4;
        *reinterpret_cast<float4*>(pooled + (size_t)g * KP * 96 + r * 96 + c4) =
            *reinterpret_cast<const float4*>(xc + ((size_t)g * NPG + sel[r]) * 96 + c4);
    }
}

// ---------------- capsule-1 priors: 256x128 tile, 512 thr, 8x8/thread, K-split LDS ----------------
__global__ __launch_bounds__(512, 2) void k_priors1(const float* __restrict__ pooled,
                                                    const float* __restrict__ Wc1,
                                                    float* __restrict__ priors) {
    int bid = blockIdx.x;
    int ct = bid & 3;          // 4 col tiles of 128
    int bt = (bid >> 2) & 1;   // 2 row tiles of 256
    int i = bid >> 3;          // 50
    __shared__ float As[48 * 256];  // 48 KiB, k-major, XOR-swizzled 4-float groups
    __shared__ float Bs[48 * 128];  // 24 KiB
    int t = threadIdx.x;
    int tx = t & 15, ty = t >> 4;  // ty 0..31
    float acc[8][8];
#pragma unroll
    for (int r = 0; r < 8; ++r)
#pragma unroll
        for (int c = 0; c < 8; ++c) acc[r][c] = 0.f;

    for (int kh = 0; kh < 2; ++kh) {
        int kbase = kh * 48;
        __syncthreads();
        for (int idx = t; idx < 256 * 12; idx += 512) {
            int r = idx / 12, c4 = (idx % 12) * 4;
            int b = bt * 256 + r;
            float4 v = make_float4(0.f, 0.f, 0.f, 0.f);
            if (b < NGRAPH)
                v = *reinterpret_cast<const float4*>(pooled + ((size_t)b * KP + i) * 96 + kbase + c4);
            float vv[4] = {v.x, v.y, v.z, v.w};
#pragma unroll
            for (int j = 0; j < 4; ++j) {
                int k = c4 + j;
                int gp = (r >> 2) ^ ((k >> 2) & 31);
                As[k * 256 + gp * 4 + (r & 3)] = vv[j];
            }
        }
        for (int idx = t; idx < 128 * 12; idx += 512) {
            int c = idx / 12, c4 = (idx % 12) * 4;
            int col = ct * 128 + c;
            const float* wr = Wc1 + (((size_t)(col >> 5) * KP + i) * 32 + (col & 31)) * 96;
            float4 v = *reinterpret_cast<const float4*>(wr + kbase + c4);
            float vv[4] = {v.x, v.y, v.z, v.w};
#pragma unroll
            for (int j = 0; j < 4; ++j) {
                int k = c4 + j;
                int gp = (c >> 2) ^ ((k >> 2) & 31);
                Bs[k * 128 + gp * 4 + (c & 3)] = vv[j];
            }
        }
        __syncthreads();
        for (int k = 0; k < 48; ++k) {
            int key = (k >> 2) & 31;
            float4 a0 = *reinterpret_cast<const float4*>(&As[k * 256 + 4 * (ty ^ key)]);
            float4 a1 = *reinterpret_cast<const float4*>(&As[k * 256 + 4 * ((32 + ty) ^ key)]);
            float4 b0 = *reinterpret_cast<const float4*>(&Bs[k * 128 + 4 * (tx ^ key)]);
            float4 b1 = *reinterpret_cast<const float4*>(&Bs[k * 128 + 4 * ((16 + tx) ^ key)]);
            float a[8] = {a0.x, a0.y, a0.z, a0.w, a1.x, a1.y, a1.z, a1.w};
            float bb[8] = {b0.x, b0.y, b0.z, b0.w, b1.x, b1.y, b1.z, b1.w};
#pragma unroll
            for (int r = 0; r < 8; ++r)
#pragma unroll
                for (int c = 0; c < 8; ++c) acc[r][c] += a[r] * bb[c];
        }
    }
#pragma unroll
    for (int rh = 0; rh < 2; ++rh)
#pragma unroll
        for (int rr = 0; rr < 4; ++rr) {
            int b = bt * 256 + rh * 128 + ty * 4 + rr;
            if (b >= NGRAPH) continue;
#pragma unroll
            for (int ch = 0; ch < 2; ++ch) {
                int col = ct * 128 + ch * 64 + tx * 4;
                int o = col >> 5, L = col & 31;
                float4 v = make_float4(acc[rh * 4 + rr][ch * 4 + 0],
                                       acc[rh * 4 + rr][ch * 4 + 1],
                                       acc[rh * 4 + rr][ch * 4 + 2],
                                       acc[rh * 4 + rr][ch * 4 + 3]);
                *reinterpret_cast<float4*>(priors + (((size_t)b * 16 + o) * KP + i) * 32 + L) = v;
            }
        }
}

// ---------------- capsule-1 routing (per graph, all in LDS) ----------------
__global__ __launch_bounds__(256) void k_routing1(const float* __restrict__ priors_g,
                                                  float* __restrict__ v_out) {
    int b = blockIdx.x;
    __shared__ float P[16 * KP * 33];
    __shared__ float logits[16 * KP];
    __shared__ float c[16 * KP];
    __shared__ float s[16 * 32];
    __shared__ float v[16 * 32];
    __shared__ float scale[16];
    int t = threadIdx.x;
    const float* pg = priors_g + (size_t)b * (16 * KP * 32);
    for (int idx = t; idx < 16 * KP * 32; idx += 256)
        P[(idx >> 5) * 33 + (idx & 31)] = pg[idx];
    for (int idx = t; idx < 16 * KP; idx += 256) logits[idx] = 0.f;
    __syncthreads();
    for (int it = 0; it < 3; ++it) {
        if (t < KP) {
            float m = -1e30f;
            for (int o = 0; o < 16; ++o) m = fmaxf(m, logits[o * KP + t]);
            float sum = 0.f;
            for (int o = 0; o < 16; ++o) {
                float e = expf(logits[o * KP + t] - m);
                c[o * KP + t] = e;
                sum += e;
            }
            for (int o = 0; o < 16; ++o) c[o * KP + t] /= sum;
        }
        __syncthreads();
        for (int idx = t; idx < 16 * 32; idx += 256) {
            int o = idx >> 5, L = idx & 31;
            float acc = 0.f;
            for (int i = 0; i < KP; ++i) acc += c[o * KP + i] * P[(o * KP + i) * 33 + L];
            s[idx] = acc;
        }
        __syncthreads();
        if (t < 16) {
            float sq = 0.f;
            for (int L = 0; L < 32; ++L) sq += s[t * 32 + L] * s[t * 32 + L];
            scale[t] = (sq / (1.f + sq)) * (1.0f / sqrtf(sq + 1e-12f));
        }
        __syncthreads();
        for (int idx = t; idx < 16 * 32; idx += 256) v[idx] = s[idx] * scale[idx >> 5];
        __syncthreads();
        if (it < 2) {
            for (int idx = t; idx < 16 * KP; idx += 256) {
                int o = idx / KP, i = idx % KP;
                float acc = 0.f;
                for (int L = 0; L < 32; ++L) acc += P[(o * KP + i) * 33 + L] * v[o * 32 + L];
                logits[idx] += acc;
            }
            __syncthreads();
        }
    }
    for (int idx = t; idx < 16 * 32; idx += 256) v_out[(size_t)b * 512 + idx] = v[idx];
}

// ---------------- capsule-2: priors (into LDS) + routing + final norms ----------------
__global__ __launch_bounds__(256) void k_caps2(const float* __restrict__ v1,
                                               const float* __restrict__ Wc2,
                                               float* __restrict__ out) {
    int b = blockIdx.x;
    __shared__ float ul[16 * 32];
    __shared__ float P[NCLS * 16 * 17];
    __shared__ float logits[NCLS * 16];
    __shared__ float c[NCLS * 16];
    __shared__ float s[NCLS * 16];
    __shared__ float v[NCLS * 16];
    __shared__ float scale[NCLS];
    int t = threadIdx.x;
    for (int idx = t; idx < 512; idx += 256) ul[idx] = v1[(size_t)b * 512 + idx];
    for (int idx = t; idx < NCLS * 16; idx += 256) logits[idx] = 0.f;
    __syncthreads();
    for (int idx = t; idx < NCLS * 16 * 16; idx += 256) {
        int L = idx & 15, i = (idx >> 4) & 15, o = idx >> 8;
        const float4* wr = reinterpret_cast<const float4*>(Wc2 + ((size_t)((o * 16 + i) * 16 + L)) * 32);
        const float4* ur = reinterpret_cast<const float4*>(&ul[i * 32]);
        float acc = 0.f;
#pragma unroll
        for (int l = 0; l < 8; ++l) {
            float4 w4 = wr[l], u4 = ur[l];
            acc += w4.x * u4.x + w4.y * u4.y + w4.z * u4.z + w4.w * u4.w;
        }
        P[(idx >> 4) * 17 + L] = acc;
    }
    __syncthreads();
    for (int it = 0; it < 3; ++it) {
        if (t < 16) {
            float m = -1e30f;
            for (int o = 0; o < NCLS; ++o) m = fmaxf(m, logits[o * 16 + t]);
            float sum = 0.f;
            for (int o = 0; o < NCLS; ++o) {
                float e = expf(logits[o * 16 + t] - m);
                c[o * 16 + t] = e;
                sum += e;
            }
            for (int o = 0; o < NCLS; ++o) c[o * 16 + t] /= sum;
        }
        __syncthreads();
        if (t < NCLS * 16) {
            int o = t >> 4, L = t & 15;
            float acc = 0.f;
            for (int i = 0; i < 16; ++i) acc += c[o * 16 + i] * P[(o * 16 + i) * 17 + L];
            s[t] = acc;
        }
        __syncthreads();
        if (t < NCLS) {
            float sq = 0.f;
            for (int L = 0; L < 16; ++L) sq += s[t * 16 + L] * s[t * 16 + L];
            scale[t] = (sq / (1.f + sq)) * (1.0f / sqrtf(sq + 1e-12f));
        }
        __syncthreads();
        if (t < NCLS * 16) v[t] = s[t] * scale[t >> 4];
        __syncthreads();
        if (it < 2) {
            if (t < NCLS * 16) {
                int o = t >> 4, i = t & 15;
                float acc = 0.f;
                for (int L = 0; L < 16; ++L) acc += P[(o * 16 + i) * 17 + L] * v[o * 16 + L];
                logits[t] += acc;
            }
            __syncthreads();
        }
    }
    if (t < NCLS) {
        float sq = 0.f;
        for (int L = 0; L < 16; ++L) sq += v[t * 16 + L] * v[t * 16 + L];
        out[(size_t)b * NCLS + t] = sqrtf(sq);
    }
}

extern "C" void kernel_launch(void* const* d_in, const int* in_sizes, int n_in,
                              void* d_out, int out_size, void* d_ws, size_t ws_size,
                              hipStream_t stream) {
    const float* x   = (const float*)d_in[0];
    const int*   ei  = (const int*)d_in[1];
    const float* W1  = (const float*)d_in[3];
    const float* b1  = (const float*)d_in[4];
    const float* W2  = (const float*)d_in[5];
    const float* b2  = (const float*)d_in[6];
    const float* W3  = (const float*)d_in[7];
    const float* b3  = (const float*)d_in[8];
    const float* Wc1 = (const float*)d_in[9];
    const float* Wc2 = (const float*)d_in[10];
    float* out = (float*)d_out;
    float* wsf = (float*)d_ws;

    const int* src = ei;
    const int* dst = ei + NEDGES;

    // ---- workspace layout (float-element offsets) ----
    float* xc = wsf;                                // 9,600,000
    float* R  = wsf + 9600000;
    int*   cursor  = (int*)R;                       // 196 (pad to 256)
    float* dinv    = R + 256;                       // 100,000
    int2*  begend  = (int2*)(R + 100256);           // 100,000 int2 = 200,000
    float* A       = R + 300256;                    // shared region: csorted | h | pooled
    unsigned* csorted = (unsigned*)A;               // NB1*CAP = 3,411,968
    float* h       = A;                             // 3,200,000 (after fill2, csorted dead)
    float* pooled  = A;                             // 2,400,000 (after gather3, h dead)
    int*   csrc    = (int*)(R + 3712224);           // 3,411,968 (bucket-strided)
    float* pr1     = R + 7124192;                   // 12,800,000
    float* v1      = R + 19924192;                  // 256,000

    // ---- CSR build: single-pass bucketed placement (fixed capacity) ----
    hipMemsetAsync(cursor, 0, 256 * sizeof(int), stream);
    k_place1<<<NBLK1, 512, 0, stream>>>(src, dst, cursor, csorted);
    k_fill2<<<NB1, 512, 0, stream>>>(cursor, csorted, csrc, begend, dinv);

    // ---- layer 1 ----
    k_matmul<<<(NNODES + 255) / 256, 256, 0, stream>>>(x, FIN, FIN, W1, dinv, h);
    k_gather<<<NNODES / 8, 256, 0, stream>>>(begend, csrc, dinv, h, b1, xc, 0);
    // ---- layer 2 ----
    k_matmul<<<(NNODES + 255) / 256, 256, 0, stream>>>(xc, 96, HID, W2, dinv, h);
    k_gather<<<NNODES / 8, 256, 0, stream>>>(begend, csrc, dinv, h, b2, xc, 32);
    // ---- layer 3 ----
    k_matmul<<<(NNODES + 255) / 256, 256, 0, stream>>>(xc + 32, 96, HID, W3, dinv, h);
    k_gather<<<NNODES / 8, 256, 0, stream>>>(begend, csrc, dinv, h, b3, xc, 64);

    // ---- sort-pool + capsules ----
    k_sortpool<<<NGRAPH, 256, 0, stream>>>(xc, pooled);
    k_priors1<<<KP * 8, 512, 0, stream>>>(pooled, Wc1, pr1);
    k_routing1<<<NGRAPH, 256, 0, stream>>>(pr1, v1);
    k_caps2<<<NGRAPH, 256, 0, stream>>>(v1, Wc2, out);
}